// Round 4
// baseline (308.551 us; speedup 1.0000x reference)
//
#include <hip/hip_runtime.h>
#include <stdint.h>

#define C_ITEMS 16384
#define NCLS 16
#define HSTRIDE 16386   // AP hist entries per class (opt in [1, P+1])
#define BSTRIDE 16386   // B-table entries per class
#define PMAX 2048       // LDS-tiled path limit for P (actual P ~1024±100)

// ---- workspace layout (bytes) ----
static const size_t OFF_COL  = 0;                                     // 16*16384 f32 col-major scores
static const size_t OFF_SPOS = 1u << 20;                              // sorted positives (desc) per class
static const size_t OFF_SMV  = 2u << 20;                              // negatives sorted ascending by rank
static const size_t OFF_PACK = 3u << 20;                              // bucket-scattered (low16key,idx)
static const size_t OFF_HIST = 4u << 20;                              // 16 * HSTRIDE u32 (AP hist)
static const size_t OFF_CNT  = OFF_HIST + (size_t)NCLS * HSTRIDE * 4; // (unused, kept for layout)
static const size_t OFF_ACCS = OFF_CNT + 64;                          // 16 double
static const size_t OFF_ACCV = OFF_ACCS + 128;                        // 16 double
static const size_t OFF_TOT  = OFF_ACCV + 128;                        // 1 double
static const size_t OFF_PC   = OFF_TOT + 8;                           // 16 u32 positive counters
static const size_t OFF_H1   = (OFF_PC + 64 + 255) & ~(size_t)255;    // 16 * 65536 u32 bucket hist
static const size_t OFF_PPK  = OFF_H1 + (((size_t)NCLS << 16) * 4);   // 16 * 16384 u64 positive keys (2MB)
// Hg/Bs/part overlap the ppk region (ppk is dead after k_posrank2):
static const size_t OFF_HARM = OFF_PPK;                               // 16385 f32 harmonic table
static const size_t OFF_BS   = OFF_PPK + 0x12000;                     // 16 * BSTRIDE f32 B tables
static const size_t OFF_PART = OFF_BS + (size_t)NCLS * BSTRIDE * 4;   // 1024 u32 scan partials
static const size_t ZERO_BYTES = OFF_PPK - OFF_HIST;                  // zero hist..h1 end

__device__ __forceinline__ unsigned ordkey(float f) {
  unsigned b = __float_as_uint(f);
  return (b & 0x80000000u) ? ~b : (b | 0x80000000u);   // monotone float->uint
}

__global__ void k_zero(unsigned* p, int n) {
  int stride = gridDim.x * blockDim.x;
  for (int t = blockIdx.x * blockDim.x + threadIdx.x; t < n; t += stride) p[t] = 0u;
}

// transpose + per-class negative bucket histogram (65536 buckets on ordkey>>16)
__global__ void k_prep(const float* __restrict__ scores, const int* __restrict__ labels,
                       float* __restrict__ col, unsigned* __restrict__ h1) {
  int t = blockIdx.x * 256 + threadIdx.x;      // 0..262143
  float v = scores[t];
  int i = t >> 4, c = t & 15;
  col[(c << 14) | i] = v;
  if (labels[i] != c)
    atomicAdd(&h1[(c << 16) + (ordkey(v) >> 16)], 1u);
}

// ---- positives: collect (key,idx) per class into global lists ----
__global__ void k_poscollect(const float* __restrict__ scores, const int* __restrict__ labels,
                             unsigned* __restrict__ pcnt, unsigned long long* __restrict__ ppk) {
  int i = blockIdx.x * 256 + threadIdx.x;   // 0..16383
  int c = labels[i] & 15;
  float v = scores[i * NCLS + c];
  unsigned idx = atomicAdd(&pcnt[c], 1u);
  ppk[(c << 14) + idx] = ((unsigned long long)(~ordkey(v)) << 32) | (unsigned)i;
}

// ---- positives: rank (descending) + scatter sorted values ----
#define PCAP 4096
__global__ void k_posrank2(const float* __restrict__ scores,
                           const unsigned long long* __restrict__ ppk,
                           const unsigned* __restrict__ pcnt, float* __restrict__ spos) {
  int c = blockIdx.y;
  unsigned P = pcnt[c];
  int tid = threadIdx.x;
  __shared__ unsigned long long pk[PCAP];
  const unsigned long long* src = ppk + ((size_t)c << 14);
  if (P <= PCAP) {
    for (unsigned t = tid; t < P; t += 256) pk[t] = src[t];
    __syncthreads();
    for (unsigned q = blockIdx.x * 256 + tid; q < P; q += gridDim.x * 256) {
      unsigned long long k64 = pk[q];
      unsigned cq = 0;
      for (unsigned t = 0; t < P; ++t) cq += (pk[t] < k64) ? 1u : 0u;
      unsigned i = (unsigned)(k64 & 0xFFFFFFFFu);
      spos[(c << 14) + cq] = scores[i * NCLS + c];
    }
  } else { // safety fallback
    for (unsigned q = blockIdx.x * 256 + tid; q < P; q += gridDim.x * 256) {
      unsigned long long k64 = src[q];
      unsigned cq = 0;
      for (unsigned t = 0; t < P; ++t) cq += (src[t] < k64) ? 1u : 0u;
      unsigned i = (unsigned)(k64 & 0xFFFFFFFFu);
      spos[(c << 14) + cq] = scores[i * NCLS + c];
    }
  }
}

// ---- harmonic table H[m] = sum_{t<=m} 1/t, m in [0, 16384], fp64 scan -> f32 ----
__global__ void k_harm(float* __restrict__ Hg) {
  int tid = threadIdx.x;              // 1024 threads, 16 m's each
  int m0 = tid * 16 + 1;
  double s = 0.0;
  for (int q = 0; q < 16; ++q) s += 1.0 / (double)(m0 + q);
  __shared__ double part[1024];
  part[tid] = s;
  __syncthreads();
  for (int off = 1; off < 1024; off <<= 1) {
    double v = (tid >= off) ? part[tid - off] : 0.0;
    __syncthreads();
    part[tid] += v;
    __syncthreads();
  }
  double run = part[tid] - s;         // exclusive prefix
  for (int q = 0; q < 16; ++q) {
    run += 1.0 / (double)(m0 + q);
    Hg[m0 + q] = (float)run;
  }
  if (tid == 0) Hg[0] = 0.f;
}

// ---- per-class B table: Bs[r] = -(2/(PN)) * sum_{k>=r} sp_k, r in [1,P+1] ----
__global__ void k_btab(const float* __restrict__ spos, const unsigned* __restrict__ pcnt,
                       float* __restrict__ Bsg) {
  int c = blockIdx.x;
  int tid = threadIdx.x;
  int P = (int)pcnt[c];
  int N = C_ITEMS - P;
  if (P == 0 || N == 0) return;
  __shared__ double part[256];
  int L = (P + 255) / 256;
  int a = tid * L, b = min(a + L, P);
  double s = 0.0;
  for (int q = a; q < b; ++q) s += (double)spos[(c << 14) + q];
  part[tid] = s;
  __syncthreads();
  for (int off = 1; off < 256; off <<= 1) {
    double v = (tid >= off) ? part[tid - off] : 0.0;
    __syncthreads();
    part[tid] += v;
    __syncthreads();
  }
  double total = part[255];
  double run = part[tid] - s;         // sum spos[0..a-1]
  double coefD = 2.0 / ((double)P * (double)N);
  for (int q = a; q < b; ++q) {
    Bsg[c * BSTRIDE + q + 1] = (float)(-coefD * (total - run));  // r = q+1
    run += (double)spos[(c << 14) + q];
  }
  if (tid == 0) Bsg[c * BSTRIDE + P + 1] = 0.f;   // empty suffix
}

// ---- hierarchical exclusive scan of h1 (16 x 65536), 3 kernels ----
__global__ void k_scanA(const unsigned* __restrict__ h1, unsigned* __restrict__ part) {
  int c = blockIdx.y, b = blockIdx.x, tid = threadIdx.x;
  const uint4* hp = (const uint4*)(h1 + ((size_t)c << 16) + b * 1024);
  uint4 v = hp[tid];
  unsigned s = v.x + v.y + v.z + v.w;
  __shared__ unsigned red[256];
  red[tid] = s;
  __syncthreads();
  for (int off = 128; off > 0; off >>= 1) {
    if (tid < off) red[tid] += red[tid + off];
    __syncthreads();
  }
  if (tid == 0) part[c * 64 + b] = red[0];
}

__global__ void k_scanB(unsigned* __restrict__ part) {  // segmented (seg=64) exclusive scan of 1024
  int tid = threadIdx.x;
  unsigned s = part[tid];
  __shared__ unsigned arr[1024];
  arr[tid] = s;
  __syncthreads();
  int l = tid & 63;
  for (int off = 1; off < 64; off <<= 1) {
    unsigned v = (l >= off) ? arr[tid - off] : 0u;
    __syncthreads();
    arr[tid] += v;
    __syncthreads();
  }
  part[tid] = arr[tid] - s;
}

__global__ void k_scanC(unsigned* __restrict__ h1, const unsigned* __restrict__ part) {
  int c = blockIdx.y, b = blockIdx.x, tid = threadIdx.x;
  uint4* hp = (uint4*)(h1 + ((size_t)c << 16) + b * 1024);
  uint4 v = hp[tid];
  unsigned s = v.x + v.y + v.z + v.w;
  __shared__ unsigned red[256];
  red[tid] = s;
  __syncthreads();
  for (int off = 1; off < 256; off <<= 1) {
    unsigned t2 = (tid >= off) ? red[tid - off] : 0u;
    __syncthreads();
    red[tid] += t2;
    __syncthreads();
  }
  unsigned base = part[c * 64 + b] + red[tid] - s;
  uint4 o;
  o.x = base; o.y = base + v.x; o.z = base + v.x + v.y; o.w = base + v.x + v.y + v.z;
  hp[tid] = o;
}

// ---- scatter negatives into bucket-grouped array; h1[b] becomes bucket END ----
__global__ void k_scatter(const float* __restrict__ col, const int* __restrict__ labels,
                          unsigned* __restrict__ h1, unsigned* __restrict__ pack) {
  int t = blockIdx.x * 256 + threadIdx.x;
  int c = t >> 14, i = t & 16383;
  if (labels[i] != c) {
    unsigned k = ordkey(col[t]);
    unsigned p = atomicAdd(&h1[(c << 16) + (k >> 16)], 1u);
    pack[(c << 14) + p] = (k << 16) | (unsigned)i;
  }
}

// ---- rank = bucket start + smaller same-bucket count; emit smv[rank] = value ----
__global__ void k_rankfine(const float* __restrict__ col, const int* __restrict__ labels,
                           const unsigned* __restrict__ h1, const unsigned* __restrict__ pack,
                           float* __restrict__ smv) {
  int t = blockIdx.x * 256 + threadIdx.x;
  int c = t >> 14, i = t & 16383;
  if (labels[i] != c) {
    float v = col[t];
    unsigned k = ordkey(v);
    unsigned b = k >> 16;
    const unsigned* hb = h1 + ((size_t)c << 16);
    unsigned start = b ? hb[b - 1] : 0u;
    unsigned end = hb[b];
    unsigned mine = (k << 16) | (unsigned)i;
    const unsigned* pk = pack + (c << 14);
    unsigned cnt = start;
    for (unsigned q = start; q < end; ++q) cnt += (pk[q] < mine) ? 1u : 0u;
    smv[(c << 14) + cnt] = v;
  }
}

// ---- transposed argmax: wave handles one j (rank), 64 lanes cover r-chunks ----
// f(r) = Bs[r] - r*c_j - invP*H[j0+r];  opt = first argmax over r in [1, P+1]
__global__ __launch_bounds__(256) void k_optT(const float* __restrict__ smv,
    const unsigned* __restrict__ pcnt, const float* __restrict__ Hg,
    const float* __restrict__ Bsg, unsigned* __restrict__ hist,
    double* __restrict__ accS, double* __restrict__ accV) {
  int c = blockIdx.y;
  int P = (int)pcnt[c];
  int N = C_ITEMS - P;
  if (P == 0 || N == 0) return;
  int jb = blockIdx.x * 256;
  if (jb >= N) return;
  int tid = threadIdx.x;
  int lane = tid & 63, w = tid >> 6;
  int nch = (P + 64) >> 6;                  // ceil((P+1)/64)
  float invP = 1.0f / (float)P;
  float coef = 2.0f / ((float)P * (float)N);
  float lanef1 = (float)lane + 1.0f;
  int jw = jb + (w << 6);
  float vall = (jw + lane < N) ? smv[(c << 14) + jw + lane] : 0.f;
  int jmax = min(64, N - jw);
  double runs = 0.0, runv = 0.0;

  __shared__ float Ht[PMAX + 264];
  __shared__ float LBs[PMAX + 66];
  bool tiled = (P <= PMAX);
  if (tiled) {
    int tileN = 256 + P;
    for (int t = tid; t < tileN; t += 256) {
      int g = jb + 1 + t;
      Ht[t] = (g <= C_ITEMS) ? Hg[g] : 0.f;
    }
    int btop = nch << 6;
    for (int t = tid; t < btop; t += 256)
      LBs[t] = (t <= P) ? Bsg[c * BSTRIDE + 1 + t] : -3.0e38f;  // tail mask folds into f
    __syncthreads();
    for (int jj = 0; jj < jmax; ++jj) {
      float v = __shfl(vall, jj, 64);
      float cj = coef * v;
      float bestf = -3.0e38f, bestr = 1.0f;
      const float* hp = &Ht[(w << 6) + jj + lane];
#pragma unroll 4
      for (int ch = 0; ch < nch; ++ch) {
        float t = hp[ch << 6];
        float bsv = LBs[(ch << 6) + lane];
        float rf = lanef1 + (float)(ch << 6);
        float bf = fmaf(-cj, rf, bsv);
        float f = fmaf(-invP, t, bf);
        bool gt = f > bestf;
        bestf = gt ? f : bestf;
        bestr = gt ? rf : bestr;
      }
      for (int off = 1; off < 64; off <<= 1) {
        float of = __shfl_xor(bestf, off, 64);
        float orf = __shfl_xor(bestr, off, 64);
        bool take = (of > bestf) || (of == bestf && orf < bestr);
        bestf = take ? of : bestf;
        bestr = take ? orf : bestr;
      }
      if (lane == 0) {
        int opt = (int)bestr;
        atomicAdd(&hist[c * HSTRIDE + opt], 1u);
        runs += (double)(P + 2 - 2 * opt) * (double)v;
        runv += (double)v;
      }
    }
  } else {  // correctness fallback for huge P: global reads
    for (int jj = 0; jj < jmax; ++jj) {
      float v = __shfl(vall, jj, 64);
      float cj = coef * v;
      int j0 = jw + jj;
      float bestf = -3.0e38f, bestr = 1.0f;
      for (int ch = 0; ch < nch; ++ch) {
        int rl = (ch << 6) + lane + 1;
        float rf = (float)rl;
        float t = (j0 + rl <= C_ITEMS) ? Hg[j0 + rl] : 0.f;
        float bsv = (rl <= P + 1) ? Bsg[c * BSTRIDE + rl] : -3.0e38f;
        float bf = fmaf(-cj, rf, bsv);
        float f = fmaf(-invP, t, bf);
        bool gt = f > bestf;
        bestf = gt ? f : bestf;
        bestr = gt ? rf : bestr;
      }
      for (int off = 1; off < 64; off <<= 1) {
        float of = __shfl_xor(bestf, off, 64);
        float orf = __shfl_xor(bestr, off, 64);
        bool take = (of > bestf) || (of == bestf && orf < bestr);
        bestf = take ? of : bestf;
        bestr = take ? orf : bestr;
      }
      if (lane == 0) {
        int opt = (int)bestr;
        atomicAdd(&hist[c * HSTRIDE + opt], 1u);
        runs += (double)(P + 2 - 2 * opt) * (double)v;
        runv += (double)v;
      }
    }
  }
  if (lane == 0) {
    atomicAdd(&accS[c], runs);
    atomicAdd(&accV[c], runv);
  }
}

// ---- per-class: prefix-sum hist -> r_plus, plus-side sums, loss ----
__global__ void k_finalize(const unsigned* __restrict__ pcnt, const unsigned* __restrict__ hist,
                           const float* __restrict__ spos, const double* __restrict__ accS,
                           const double* __restrict__ accV, double* __restrict__ total) {
  int c = blockIdx.x;
  int tid = threadIdx.x;
  int P = (int)pcnt[c];
  int N = C_ITEMS - P;
  if (P == 0 || N == 0) return;
  __shared__ unsigned sc[256];
  __shared__ double red[256];
  const unsigned* h = hist + c * HSTRIDE;
  int M = P + 1;
  int L = (M + 255) / 256;
  int o0 = 1 + tid * L;
  int o1 = min(o0 + L, P + 2);
  unsigned part = 0;
  for (int o = o0; o < o1; ++o) part += h[o];
  sc[tid] = part;
  __syncthreads();
  if (tid == 0) {
    unsigned runp = 0;
    for (int t = 0; t < 256; ++t) { unsigned tmp = sc[t]; sc[t] = runp; runp += tmp; }
  }
  __syncthreads();
  unsigned run = sc[tid];
  double a1 = 0.0, a2 = 0.0, a3 = 0.0;
  for (int o = o0; o < o1; ++o) {
    run += h[o];
    if (o <= P) {
      int k0 = o - 1;
      double rp = 1.0 + (double)run;
      double spv = (double)spos[(c << 14) + k0];
      a1 += (double)(k0 + 1) / ((double)k0 + rp);
      a2 += spv * ((double)N + 2.0 - 2.0 * rp);
      a3 += spv;
    }
  }
  red[tid] = a1; __syncthreads();
  for (int s = 128; s > 0; s >>= 1) { if (tid < s) red[tid] += red[tid + s]; __syncthreads(); }
  double r1 = red[0]; __syncthreads();
  red[tid] = a2; __syncthreads();
  for (int s = 128; s > 0; s >>= 1) { if (tid < s) red[tid] += red[tid + s]; __syncthreads(); }
  double r2 = red[0]; __syncthreads();
  red[tid] = a3; __syncthreads();
  for (int s = 128; s > 0; s >>= 1) { if (tid < s) red[tid] += red[tid + s]; __syncthreads(); }
  double r3 = red[0];
  if (tid == 0) {
    double Pd = (double)P, Nd = (double)N;
    double FR  = r2 + accS[c];
    double FRs = Nd * r3 - Pd * accV[c];
    double lc  = (1.0 - r1 / Pd) + (FR - FRs) / (Pd * Nd);
    atomicAdd(total, lc);
  }
}

__global__ void k_out(const double* __restrict__ total, float* __restrict__ out) {
  out[0] = (float)(total[0] / (double)NCLS);
}

extern "C" void kernel_launch(void* const* d_in, const int* in_sizes, int n_in,
                              void* d_out, int out_size, void* d_ws, size_t ws_size,
                              hipStream_t stream) {
  (void)in_sizes; (void)n_in; (void)out_size; (void)ws_size;
  const float* scores = (const float*)d_in[0];
  const int* labels = (const int*)d_in[1];
  float* out = (float*)d_out;
  char* ws = (char*)d_ws;
  float* col      = (float*)(ws + OFF_COL);
  float* spos     = (float*)(ws + OFF_SPOS);
  float* smv      = (float*)(ws + OFF_SMV);
  unsigned* pack  = (unsigned*)(ws + OFF_PACK);
  unsigned* hist  = (unsigned*)(ws + OFF_HIST);
  double* accS    = (double*)(ws + OFF_ACCS);
  double* accV    = (double*)(ws + OFF_ACCV);
  double* total   = (double*)(ws + OFF_TOT);
  unsigned* pcnt  = (unsigned*)(ws + OFF_PC);
  unsigned* h1    = (unsigned*)(ws + OFF_H1);
  unsigned long long* ppk = (unsigned long long*)(ws + OFF_PPK);
  float* Hg       = (float*)(ws + OFF_HARM);
  float* Bsg      = (float*)(ws + OFF_BS);
  unsigned* part  = (unsigned*)(ws + OFF_PART);

  int zn = (int)(ZERO_BYTES / 4);
  k_zero<<<1024, 256, 0, stream>>>(hist, zn);               // hist..h1 contiguous
  k_prep<<<1024, 256, 0, stream>>>(scores, labels, col, h1);
  k_poscollect<<<64, 256, 0, stream>>>(scores, labels, pcnt, ppk);
  k_posrank2<<<dim3(16, NCLS), 256, 0, stream>>>(scores, ppk, pcnt, spos);
  k_harm<<<1, 1024, 0, stream>>>(Hg);                       // overwrites ppk region (now dead)
  k_btab<<<NCLS, 256, 0, stream>>>(spos, pcnt, Bsg);
  k_scanA<<<dim3(64, NCLS), 256, 0, stream>>>(h1, part);
  k_scanB<<<1, 1024, 0, stream>>>(part);
  k_scanC<<<dim3(64, NCLS), 256, 0, stream>>>(h1, part);
  k_scatter<<<1024, 256, 0, stream>>>(col, labels, h1, pack);
  k_rankfine<<<1024, 256, 0, stream>>>(col, labels, h1, pack, smv);
  k_optT<<<dim3(64, NCLS), 256, 0, stream>>>(smv, pcnt, Hg, Bsg, hist, accS, accV);
  k_finalize<<<NCLS, 256, 0, stream>>>(pcnt, hist, spos, accS, accV, total);
  k_out<<<1, 1, 0, stream>>>(total, out);
}